// Round 2
// baseline (850.592 us; speedup 1.0000x reference)
//
#include <hip/hip_runtime.h>

// ---------------------------------------------------------------------------
// FeaturePropagationLayer (PointNet++ FP): 3-NN interp -> concat -> MLP(384->256)
// -> GN(32)+ReLU -> MLP(256->128) -> GN(32)+ReLU.  Output (B,N,128).
//
// Round 1: dtype-robust correctness build.  A detect kernel classifies the
// input dtype (fp32 vs bf16) from xyz1's bit pattern into a device flag; all
// input loads / the final store branch on it (wave-uniform).  Intermediates
// are fp32 in d_ws.  GEMMs are classic 64x64 LDS-tiled VALU fp32 (no MFMA yet).
// ---------------------------------------------------------------------------

#define DEVI __device__ __forceinline__

static constexpr int B  = 8;
static constexpr int N  = 8192;
static constexpr int M  = 2048;
static constexpr int C1 = 128;
static constexpr int C2 = 256;
static constexpr int CIN = C1 + C2;   // 384
static constexpr int H0 = 256;
static constexpr int H1 = 128;
static constexpr int BN = B * N;      // 65536

DEVI float bf2f(unsigned short u) {
    union { unsigned int i; float f; } v; v.i = ((unsigned int)u) << 16; return v.f;
}
DEVI unsigned short f2bf(float f) {
    union { float f; unsigned int i; } v; v.f = f;
    unsigned int x = v.i;
    return (unsigned short)((x + 0x7fffu + ((x >> 16) & 1u)) >> 16);
}
// Flagged scalar input load: bf==1 -> bf16, else fp32.
DEVI float ldin(const void* p, size_t i, int bf) {
    return bf ? bf2f(((const unsigned short*)p)[i]) : ((const float*)p)[i];
}

// ---------------------------------------------------------------------------
// K0: dtype detect.  For fp32 N(0,1) data, ushort[2*lane] is a raw mantissa
// word -> bf16 view almost never lands in [1e-4,100].  For bf16 data it
// almost always does.  One wave, ballot, majority vote.
// ---------------------------------------------------------------------------
__global__ __launch_bounds__(64) void detect_dtype_kernel(const void* __restrict__ xyz1,
                                                          int* __restrict__ flag)
{
    const unsigned short* u = (const unsigned short*)xyz1;
    const int lane = threadIdx.x;
    const float av = fabsf(bf2f(u[2 * lane]));
    const bool in_range = (av >= 1e-4f && av <= 100.0f);
    const unsigned long long m = __ballot(in_range);
    if (lane == 0) flag[0] = (__popcll(m) >= 32) ? 1 : 0;
}

// ---------------------------------------------------------------------------
// K1: 3-NN search.  One thread per query point; xyz2 tiles staged in LDS.
// Expanded-form distance in fp32, no fma contraction (matches reference).
// Strict < keeps lower index on ties (lax.top_k stability).
// ---------------------------------------------------------------------------
__global__ __launch_bounds__(256) void knn3_kernel(
    const void* __restrict__ xyz1, const void* __restrict__ xyz2,
    int* __restrict__ nn_idx, float* __restrict__ nn_w,
    const int* __restrict__ flag)
{
    const int bf = flag[0];
    const int tid = threadIdx.x;
    const int gid = blockIdx.x * 256 + tid;        // b*N + n
    const int b = gid >> 13;                       // /8192

    const float x1 = ldin(xyz1, (size_t)gid * 3 + 0, bf);
    const float y1 = ldin(xyz1, (size_t)gid * 3 + 1, bf);
    const float z1 = ldin(xyz1, (size_t)gid * 3 + 2, bf);
    const float sq1 = __fadd_rn(__fadd_rn(__fmul_rn(x1, x1), __fmul_rn(y1, y1)), __fmul_rn(z1, z1));

    float b0 = 3.4e38f, b1 = 3.4e38f, b2 = 3.4e38f;
    int   i0 = 0, i1 = 0, i2 = 0;

    __shared__ float sx[256], sy[256], sz[256], sq[256];

    for (int j0 = 0; j0 < M; j0 += 256) {
        const int j = j0 + tid;
        const float x2 = ldin(xyz2, (size_t)(b * M + j) * 3 + 0, bf);
        const float y2 = ldin(xyz2, (size_t)(b * M + j) * 3 + 1, bf);
        const float z2 = ldin(xyz2, (size_t)(b * M + j) * 3 + 2, bf);
        sx[tid] = x2; sy[tid] = y2; sz[tid] = z2;
        sq[tid] = __fadd_rn(__fadd_rn(__fmul_rn(x2, x2), __fmul_rn(y2, y2)), __fmul_rn(z2, z2));
        __syncthreads();
        for (int jj = 0; jj < 256; jj++) {
            const float inner = __fadd_rn(__fadd_rn(__fmul_rn(x1, sx[jj]), __fmul_rn(y1, sy[jj])),
                                          __fmul_rn(z1, sz[jj]));
            const float d = __fadd_rn(__fsub_rn(sq1, __fmul_rn(2.0f, inner)), sq[jj]);
            const int j2 = j0 + jj;
            if (d < b2) {
                if (d < b0)      { b2 = b1; i2 = i1; b1 = b0; i1 = i0; b0 = d; i0 = j2; }
                else if (d < b1) { b2 = b1; i2 = i1; b1 = d;  i1 = j2; }
                else             { b2 = d;  i2 = j2; }
            }
        }
        __syncthreads();
    }

    const float v0 = 1.0f / (b0 + 1e-8f);
    const float v1 = 1.0f / (b1 + 1e-8f);
    const float v2 = 1.0f / (b2 + 1e-8f);
    const float s = v0 + v1 + v2;
    nn_idx[gid * 3 + 0] = i0; nn_idx[gid * 3 + 1] = i1; nn_idx[gid * 3 + 2] = i2;
    nn_w[gid * 3 + 0] = v0 / s; nn_w[gid * 3 + 1] = v1 / s; nn_w[gid * 3 + 2] = v2 / s;
}

// ---------------------------------------------------------------------------
// K2: interpolate + concat -> feat (BN, 384) fp32
// ---------------------------------------------------------------------------
__global__ __launch_bounds__(256) void interp_concat_kernel(
    const void* __restrict__ p1, const void* __restrict__ p2,
    const int* __restrict__ nn_idx, const float* __restrict__ nn_w,
    float* __restrict__ feat, const int* __restrict__ flag)
{
    const int bf = flag[0];
    const int total = BN * CIN;
    for (int i = blockIdx.x * blockDim.x + threadIdx.x; i < total; i += gridDim.x * blockDim.x) {
        const int c = i % CIN;
        const int p = i / CIN;
        float v;
        if (c < C1) {
            v = ldin(p1, (size_t)p * C1 + c, bf);
        } else {
            const int b = p >> 13;
            const int c2 = c - C1;
            const int*   id = nn_idx + p * 3;
            const float* w  = nn_w  + p * 3;
            v = w[0] * ldin(p2, (size_t)(b * M + id[0]) * C2 + c2, bf)
              + w[1] * ldin(p2, (size_t)(b * M + id[1]) * C2 + c2, bf)
              + w[2] * ldin(p2, (size_t)(b * M + id[2]) * C2 + c2, bf);
        }
        feat[i] = v;
    }
}

// ---------------------------------------------------------------------------
// K3/K6: C = A (rows,K fp32) * W^T (Cout,K flagged dtype), fp32 out.
// 64x64 block tile, 256 threads, 4x4 microtile, K-tile 16.
// ---------------------------------------------------------------------------
__global__ __launch_bounds__(256) void gemm_nt_kernel(
    const float* __restrict__ A, const void* __restrict__ W,
    float* __restrict__ Cmat, int K, int Cout, const int* __restrict__ flag)
{
    const int bf = flag[0];
    __shared__ float As[64][17];
    __shared__ float Ws[64][17];

    const int tid = threadIdx.x;
    const int rowBase = blockIdx.x * 64;
    const int colBase = blockIdx.y * 64;
    const int tx = tid & 15, ty = tid >> 4;

    float acc[4][4];
#pragma unroll
    for (int i = 0; i < 4; i++)
#pragma unroll
        for (int j = 0; j < 4; j++) acc[i][j] = 0.f;

    const int lr = (tid * 4) >> 4;   // load row within tile [0,64)
    const int lk = (tid * 4) & 15;   // load k offset {0,4,8,12}

    for (int k0 = 0; k0 < K; k0 += 16) {
        const float4 a4 = *(const float4*)(A + (size_t)(rowBase + lr) * K + k0 + lk);
        As[lr][lk + 0] = a4.x; As[lr][lk + 1] = a4.y;
        As[lr][lk + 2] = a4.z; As[lr][lk + 3] = a4.w;
        if (bf) {
            const ushort4 w4 = *(const ushort4*)((const unsigned short*)W + (size_t)(colBase + lr) * K + k0 + lk);
            Ws[lr][lk + 0] = bf2f(w4.x); Ws[lr][lk + 1] = bf2f(w4.y);
            Ws[lr][lk + 2] = bf2f(w4.z); Ws[lr][lk + 3] = bf2f(w4.w);
        } else {
            const float4 w4 = *(const float4*)((const float*)W + (size_t)(colBase + lr) * K + k0 + lk);
            Ws[lr][lk + 0] = w4.x; Ws[lr][lk + 1] = w4.y;
            Ws[lr][lk + 2] = w4.z; Ws[lr][lk + 3] = w4.w;
        }
        __syncthreads();
#pragma unroll
        for (int k = 0; k < 16; k++) {
            const float a0 = As[ty * 4 + 0][k], a1 = As[ty * 4 + 1][k];
            const float a2 = As[ty * 4 + 2][k], a3 = As[ty * 4 + 3][k];
            const float w0v = Ws[tx * 4 + 0][k], w1v = Ws[tx * 4 + 1][k];
            const float w2v = Ws[tx * 4 + 2][k], w3v = Ws[tx * 4 + 3][k];
            acc[0][0] += a0 * w0v; acc[0][1] += a0 * w1v; acc[0][2] += a0 * w2v; acc[0][3] += a0 * w3v;
            acc[1][0] += a1 * w0v; acc[1][1] += a1 * w1v; acc[1][2] += a1 * w2v; acc[1][3] += a1 * w3v;
            acc[2][0] += a2 * w0v; acc[2][1] += a2 * w1v; acc[2][2] += a2 * w2v; acc[2][3] += a2 * w3v;
            acc[3][0] += a3 * w0v; acc[3][1] += a3 * w1v; acc[3][2] += a3 * w2v; acc[3][3] += a3 * w3v;
        }
        __syncthreads();
    }

#pragma unroll
    for (int i = 0; i < 4; i++) {
        const size_t row = rowBase + ty * 4 + i;
        float4 o; o.x = acc[i][0]; o.y = acc[i][1]; o.z = acc[i][2]; o.w = acc[i][3];
        *(float4*)(Cmat + row * Cout + colBase + tx * 4) = o;
    }
}

// ---------------------------------------------------------------------------
// K4/K7: GroupNorm stats.  One block per (batch, group); mean + rstd fp32.
// ---------------------------------------------------------------------------
__global__ __launch_bounds__(256) void gn_stats_kernel(
    const float* __restrict__ h, float2* __restrict__ st, int C, int cpg)
{
    const int groups = C / cpg;
    const int b = blockIdx.x / groups;
    const int g = blockIdx.x % groups;

    float s = 0.f, ss = 0.f;
    for (int n = threadIdx.x; n < N; n += 256) {
        const float* row = h + (size_t)(b * N + n) * C + g * cpg;
        for (int c = 0; c < cpg; c += 4) {
            const float4 v = *(const float4*)(row + c);
            s  += v.x + v.y + v.z + v.w;
            ss += v.x * v.x + v.y * v.y + v.z * v.z + v.w * v.w;
        }
    }
    __shared__ float rs[256], rss[256];
    rs[threadIdx.x] = s; rss[threadIdx.x] = ss;
    __syncthreads();
    for (int off = 128; off > 0; off >>= 1) {
        if (threadIdx.x < off) {
            rs[threadIdx.x]  += rs[threadIdx.x + off];
            rss[threadIdx.x] += rss[threadIdx.x + off];
        }
        __syncthreads();
    }
    if (threadIdx.x == 0) {
        const float cnt = (float)N * (float)cpg;
        const float mu  = rs[0] / cnt;
        const float var = rss[0] / cnt - mu * mu;
        st[blockIdx.x] = make_float2(mu, rsqrtf(var + 1e-5f));
    }
}

// ---------------------------------------------------------------------------
// K5/K8: normalize + affine + ReLU.  out_flagged=0 -> fp32 ws buffer;
// out_flagged=1 -> final output, dtype per flag.
// ---------------------------------------------------------------------------
__global__ __launch_bounds__(256) void gn_norm_relu_kernel(
    const float* __restrict__ h, const float2* __restrict__ st,
    const void* __restrict__ gw, const void* __restrict__ gb,
    void* __restrict__ out, int C, int cpg, int total4,
    const int* __restrict__ flag, int out_flagged)
{
    const int bf = flag[0];
    const int C4 = C >> 2;
    for (int i4 = blockIdx.x * blockDim.x + threadIdx.x; i4 < total4; i4 += gridDim.x * blockDim.x) {
        const int c = (i4 % C4) * 4;
        const int p = i4 / C4;
        const int b = p >> 13;
        const float2 ms = st[b * (C / cpg) + c / cpg];   // 4 consecutive c share a group (cpg>=4)
        const float4 hv = *(const float4*)(h + (size_t)i4 * 4);
        float r[4];
        r[0] = hv.x; r[1] = hv.y; r[2] = hv.z; r[3] = hv.w;
#pragma unroll
        for (int k = 0; k < 4; k++) {
            const float gwv = ldin(gw, c + k, bf);
            const float gbv = ldin(gb, c + k, bf);
            r[k] = fmaxf((r[k] - ms.x) * ms.y * gwv + gbv, 0.f);
        }
        if (out_flagged && bf) {
            ushort4 o;
            o.x = f2bf(r[0]); o.y = f2bf(r[1]); o.z = f2bf(r[2]); o.w = f2bf(r[3]);
            *(ushort4*)((unsigned short*)out + (size_t)i4 * 4) = o;
        } else {
            float4 o; o.x = r[0]; o.y = r[1]; o.z = r[2]; o.w = r[3];
            *(float4*)((float*)out + (size_t)i4 * 4) = o;
        }
    }
}

// ---------------------------------------------------------------------------
extern "C" void kernel_launch(void* const* d_in, const int* in_sizes, int n_in,
                              void* d_out, int out_size, void* d_ws, size_t ws_size,
                              hipStream_t stream)
{
    const void* xyz1    = d_in[0];
    const void* xyz2    = d_in[1];
    const void* points1 = d_in[2];
    const void* points2 = d_in[3];
    const void* w0      = d_in[4];
    const void* w1      = d_in[5];
    const void* gn0w    = d_in[6];
    const void* gn0b    = d_in[7];
    const void* gn1w    = d_in[8];
    const void* gn1b    = d_in[9];

    char* ws = (char*)d_ws;
    int*    nn_idx = (int*)ws;                         //      0 ..    786432
    float*  nn_w   = (float*)(ws + 786432);            //         ..   1572864
    float*  feat   = (float*)(ws + 1572864);           // BN*384*4 -> 102236160
    float*  h0     = (float*)(ws + 102236160);         // BN*256*4 -> 169345024
    float*  h0n    = feat;                             // feat dead after GEMM1
    float*  h1     = h0;                               // h0 dead after norm0
    float2* st0    = (float2*)(ws + 169345024);        // 2 KiB
    float2* st1    = (float2*)(ws + 169347072);        // 2 KiB
    int*    flag   = (int*)(ws + 169349120);           // 4 B

    detect_dtype_kernel<<<1, 64, 0, stream>>>(xyz1, flag);

    knn3_kernel<<<BN / 256, 256, 0, stream>>>(xyz1, xyz2, nn_idx, nn_w, flag);

    interp_concat_kernel<<<8192, 256, 0, stream>>>(points1, points2, nn_idx, nn_w, feat, flag);

    {
        dim3 g(BN / 64, H0 / 64);
        gemm_nt_kernel<<<g, 256, 0, stream>>>(feat, w0, h0, CIN, H0, flag);
    }

    gn_stats_kernel<<<B * 32, 256, 0, stream>>>(h0, st0, H0, H0 / 32);
    gn_norm_relu_kernel<<<8192, 256, 0, stream>>>(h0, st0, gn0w, gn0b, (void*)h0n,
                                                  H0, H0 / 32, BN * H0 / 4, flag, 0);

    {
        dim3 g(BN / 64, H1 / 64);
        gemm_nt_kernel<<<g, 256, 0, stream>>>(h0n, w1, h1, H0, H1, flag);
    }

    gn_stats_kernel<<<B * 32, 256, 0, stream>>>(h1, st1, H1, H1 / 32);
    gn_norm_relu_kernel<<<4096, 256, 0, stream>>>(h1, st1, gn1w, gn1b, d_out,
                                                  H1, H1 / 32, BN * H1 / 4, flag, 1);
}